// Round 6
// baseline (1344.476 us; speedup 1.0000x reference)
//
#include <hip/hip_runtime.h>

#define D 64
#define SCAN_CHUNK 1024
#define MAX_CHUNKS 128
#define BSHIFT 9                 // 512 nodes per bucket
#define BNODES (1 << BSHIFT)
#define CHUNK 8192               // edges per partition block

__device__ int g_partials[MAX_CHUNKS];

// ------------------------------------------------ exclusive scan (3 kernels)
__global__ __launch_bounds__(256) void scanA(const int* __restrict__ cnt, int n) {
    __shared__ int red[256];
    int b = blockIdx.x, t = threadIdx.x;
    int base = b * SCAN_CHUNK + t * 4;
    int s = 0;
#pragma unroll
    for (int j = 0; j < 4; ++j) {
        int i = base + j;
        if (i < n) s += cnt[i];
    }
    red[t] = s;
    __syncthreads();
    for (int off = 128; off > 0; off >>= 1) {
        if (t < off) red[t] += red[t + off];
        __syncthreads();
    }
    if (t == 0) g_partials[b] = red[0];
}

__global__ __launch_bounds__(128) void scanB(int nchunks) {
    __shared__ int sh[MAX_CHUNKS];
    int t = threadIdx.x;
    int v = (t < nchunks) ? g_partials[t] : 0;
    sh[t] = v;
    __syncthreads();
    for (int off = 1; off < MAX_CHUNKS; off <<= 1) {
        int a = (t >= off) ? sh[t - off] : 0;
        __syncthreads();
        sh[t] += a;
        __syncthreads();
    }
    if (t < nchunks) g_partials[t] = sh[t] - v;  // exclusive
}

// out-of-place: offs[i] = exclusive_prefix(cnt)[i]  (cnt preserved)
__global__ __launch_bounds__(256) void scanC(const int* __restrict__ cnt,
                                             int* __restrict__ offs, int n) {
    __shared__ int sums[256];
    int b = blockIdx.x, t = threadIdx.x;
    int base = b * SCAN_CHUNK + t * 4;
    int v[4];
    int tot = 0;
#pragma unroll
    for (int j = 0; j < 4; ++j) {
        int i = base + j;
        v[j] = (i < n) ? cnt[i] : 0;
        tot += v[j];
    }
    sums[t] = tot;
    __syncthreads();
    for (int off = 1; off < 256; off <<= 1) {
        int a = (t >= off) ? sums[t - off] : 0;
        __syncthreads();
        sums[t] += a;
        __syncthreads();
    }
    int run = sums[t] - tot + g_partials[b];
#pragma unroll
    for (int j = 0; j < 4; ++j) {
        int i = base + j;
        if (i < n) offs[i] = run;
        run += v[j];
    }
}

// ------------------------------------------------ partAB: per-(chunk,bucket) counts for dst AND src
__global__ __launch_bounds__(256) void partAB(const int* __restrict__ src,
                                              const int* __restrict__ dst,
                                              int* __restrict__ histJ,
                                              int E, int G, int NB, int HL) {
    __shared__ int hD[256], hS[256];
    int g = blockIdx.x;
    hD[threadIdx.x] = 0;
    hS[threadIdx.x] = 0;
    __syncthreads();
    int base = g * CHUNK;
    int lim = min(E - base, CHUNK);
    for (int i = threadIdx.x; i < lim; i += 256) {
        atomicAdd(&hD[dst[base + i] >> BSHIFT], 1);
        atomicAdd(&hS[src[base + i] >> BSHIFT], 1);
    }
    __syncthreads();
    if (threadIdx.x < NB) {
        histJ[threadIdx.x * G + g] = hD[threadIdx.x];
        histJ[HL + threadIdx.x * G + g] = hS[threadIdx.x];
    }
}

// ------------------------------------------------ partCJ: bucket-major reorder for both partitions (SoA)
__global__ __launch_bounds__(256) void partCJ(const int* __restrict__ src,
                                              const int* __restrict__ dst,
                                              const int* __restrict__ histJs,
                                              int* __restrict__ ebufS, int* __restrict__ ebufD,
                                              int* __restrict__ ebufK,
                                              int E, int G, int NB, int HL) {
    __shared__ int curD[256], curK[256];
    int g = blockIdx.x;
    if (threadIdx.x < NB) {
        curD[threadIdx.x] = histJs[threadIdx.x * G + g];
        curK[threadIdx.x] = histJs[HL + threadIdx.x * G + g];
    }
    __syncthreads();
    int base = g * CHUNK;
    int lim = min(E - base, CHUNK);
    for (int i = threadIdx.x; i < lim; i += 256) {
        int d = dst[base + i];
        int s = src[base + i];
        int pD = atomicAdd(&curD[d >> BSHIFT], 1);
        ebufS[pD] = s;
        ebufD[pD] = d;
        int pK = atomicAdd(&curK[s >> BSHIFT], 1) - E;  // src positions offset by E in joint scan
        ebufK[pK] = s;
    }
}

// ------------------------------------------------ partDcount: per-bucket node degrees (LDS), coalesced writes
__global__ __launch_bounds__(256) void partDcount(const int* __restrict__ ebufD,
                                                  const int* __restrict__ ebufK,
                                                  const int* __restrict__ histJs,
                                                  int* __restrict__ cnt_dst, float* __restrict__ rs_src,
                                                  int E, int G, int NB, int HL, int N) {
    __shared__ int cntD[BNODES], cntS[BNODES];
    int b = blockIdx.x;
    int nbase = b << BSHIFT;
    for (int i = threadIdx.x; i < BNODES; i += 256) { cntD[i] = 0; cntS[i] = 0; }
    __syncthreads();
    int dS = histJs[b * G];
    int dE = (b + 1 < NB) ? histJs[(b + 1) * G] : E;
    for (int p = dS + threadIdx.x; p < dE; p += 256)
        atomicAdd(&cntD[ebufD[p] - nbase], 1);
    int kS = histJs[HL + b * G] - E;
    int kE = (b + 1 < NB) ? histJs[HL + (b + 1) * G] - E : E;
    for (int p = kS + threadIdx.x; p < kE; p += 256)
        atomicAdd(&cntS[ebufK[p] - nbase], 1);
    __syncthreads();
    for (int i = threadIdx.x; i < BNODES; i += 256) {
        int node = nbase + i;
        if (node < N) {
            cnt_dst[node] = cntD[i];
            rs_src[node] = rsqrtf((float)max(cntS[i], 1));
        }
    }
}

// ------------------------------------------------ partD2: per-bucket local scatter (LDS cursors)
__global__ __launch_bounds__(256) void partD2(const int* __restrict__ ebufS,
                                              const int* __restrict__ ebufD,
                                              const int* __restrict__ histJs,
                                              const int* __restrict__ offs,
                                              int* __restrict__ sortedSrc,
                                              int E, int G, int NB, int N) {
    __shared__ int cur[BNODES];
    int b = blockIdx.x;
    int nbase = b << BSHIFT;
    for (int i = threadIdx.x; i < BNODES; i += 256) {
        int node = nbase + i;
        cur[i] = (node < N) ? offs[node] : 0;
    }
    __syncthreads();
    int dS = histJs[b * G];
    int dE = (b + 1 < NB) ? histJs[(b + 1) * G] : E;
    for (int p = dS + threadIdx.x; p < dE; p += 256) {
        int d = ebufD[p];
        int s = ebufS[p];
        int pos = atomicAdd(&cur[d - nbase], 1);
        sortedSrc[pos] = s;
    }
}

// ------------------------------------------------ gather: S[i] = rs_dst[i] * sum rs_src[sj] * X[sj]
__global__ __launch_bounds__(256) void gather_kernel(
    const int* __restrict__ offs, const int* __restrict__ cnt_dst,
    const int* __restrict__ sortedSrc, const float* __restrict__ rs_src,
    const float* __restrict__ X, float* __restrict__ S, int n) {
    int lane = threadIdx.x & 63;
    int node = blockIdx.x * 4 + (threadIdx.x >> 6);
    if (node >= n) return;
    int start = offs[node];
    int cnt = cnt_dst[node];
    int end = start + cnt;
    float acc = 0.0f;
    int p = start;
    for (; p + 8 <= end; p += 8) {
        int idx[8];
        float w[8];
        float r[8];
#pragma unroll
        for (int j = 0; j < 8; ++j) idx[j] = sortedSrc[p + j];
#pragma unroll
        for (int j = 0; j < 8; ++j) w[j] = rs_src[idx[j]];
#pragma unroll
        for (int j = 0; j < 8; ++j) r[j] = X[(size_t)idx[j] * D + lane];
#pragma unroll
        for (int j = 0; j < 8; ++j) acc = fmaf(w[j], r[j], acc);
    }
    if (p < end) {  // clamped predicated tail: loads stay independent
        int idx[8];
        float w[8];
        float r[8];
#pragma unroll
        for (int j = 0; j < 8; ++j) {
            int q = p + j;
            int qc = (q < end) ? q : (end - 1);
            idx[j] = sortedSrc[qc];
        }
#pragma unroll
        for (int j = 0; j < 8; ++j) w[j] = (p + j < end) ? rs_src[idx[j]] : 0.0f;
#pragma unroll
        for (int j = 0; j < 8; ++j) r[j] = X[(size_t)idx[j] * D + lane];
#pragma unroll
        for (int j = 0; j < 8; ++j) acc = fmaf(w[j], r[j], acc);
    }
    float rd = rsqrtf((float)max(cnt, 1));
    S[(size_t)node * D + lane] = acc * rd;
}

// ------------------------------------------------ combine: Out = (X+S)@W1 + (X*S)@W2
// Thread per row. X row staged in regs (also makes layer-2 X==Out alias safe:
// all X reads precede first store). Two 32-col half-passes -> acc[32] live.
// launch_bounds(256,2): allow up to 256 VGPR so the allocator can't spill-for-occupancy.
__global__ __launch_bounds__(256, 2) void combine_kernel(
    const float* X, const float* S,
    const float* __restrict__ W1, const float* __restrict__ W2,
    float* Out, int n, int relu_flag) {
    int row = blockIdx.x * blockDim.x + threadIdx.x;
    if (row >= n) return;
    const float4* x4p = (const float4*)(X + (size_t)row * D);
    const float4* s4p = (const float4*)(S + (size_t)row * D);
    float4* o4 = (float4*)(Out + (size_t)row * D);

    float4 xr[16];
#pragma unroll
    for (int i = 0; i < 16; ++i) xr[i] = x4p[i];   // fully unrolled: static indices

#pragma unroll
    for (int half = 0; half < 2; ++half) {
        const float* Wa = W1 + half * 32;
        const float* Wb = W2 + half * 32;
        float acc[32];
#pragma unroll
        for (int c = 0; c < 32; ++c) acc[c] = 0.0f;
#pragma unroll
        for (int kk = 0; kk < 16; ++kk) {
            float4 sc = s4p[kk];                   // re-streamed per half (L1-hot 2nd pass)
            float xv[4] = {xr[kk].x, xr[kk].y, xr[kk].z, xr[kk].w};
            float sv[4] = {sc.x, sc.y, sc.z, sc.w};
#pragma unroll
            for (int j = 0; j < 4; ++j) {
                int k = (kk << 2) + j;
                float u = xv[j] + sv[j];
                float v = xv[j] * sv[j];
#pragma unroll
                for (int c = 0; c < 32; ++c) {
                    acc[c] = fmaf(u, Wa[k * D + c], acc[c]);   // wave-uniform -> s_load
                    acc[c] = fmaf(v, Wb[k * D + c], acc[c]);
                }
            }
        }
#pragma unroll
        for (int cc = 0; cc < 8; ++cc) {
            float4 o = make_float4(acc[cc * 4 + 0], acc[cc * 4 + 1],
                                   acc[cc * 4 + 2], acc[cc * 4 + 3]);
            if (relu_flag) {
                o.x = fmaxf(o.x, 0.0f); o.y = fmaxf(o.y, 0.0f);
                o.z = fmaxf(o.z, 0.0f); o.w = fmaxf(o.w, 0.0f);
            }
            o4[half * 8 + cc] = o;
        }
    }
}

extern "C" void kernel_launch(void* const* d_in, const int* in_sizes, int n_in,
                              void* d_out, int out_size, void* d_ws, size_t ws_size,
                              hipStream_t stream) {
    const float* x    = (const float*)d_in[0];
    const int*   src  = (const int*)d_in[1];
    const int*   dst  = (const int*)d_in[2];
    const float* W1_1 = (const float*)d_in[3];
    const float* W2_1 = (const float*)d_in[4];
    const float* W1_2 = (const float*)d_in[5];
    const float* W2_2 = (const float*)d_in[6];
    float* out = (float*)d_out;

    const int N = in_sizes[0] / D;
    const int E = in_sizes[1];

    const int NB = (N + BNODES - 1) >> BSHIFT;     // node buckets (196 for N=100000)
    const int G  = (E + CHUNK - 1) / CHUNK;        // partition chunks (196)
    const int HL = NB * G;

    // ws layout (4B units):
    // cnt_dst[N] | offs[N] | rs_src[N] | sortedSrc[E] | histJ[2HL] | histJs[2HL] | S[N*D]
    // ebufS/ebufD/ebufK alias S (19.2MB < 25.6MB; all dead before gather writes S).
    int*   cnt_dst   = (int*)d_ws;
    int*   offs      = cnt_dst + N;
    float* rs_src    = (float*)(cnt_dst + 2 * (size_t)N);
    int*   sortedSrc = cnt_dst + 3 * (size_t)N;
    int*   histJ     = sortedSrc + E;
    int*   histJs    = histJ + 2 * (size_t)HL;
    float* S         = (float*)(histJs + 2 * (size_t)HL);
    int*   ebufS     = (int*)S;
    int*   ebufD     = ebufS + E;
    int*   ebufK     = ebufD + E;

    const int tb = 256;
    const int n_blocks = (N + tb - 1) / tb;
    const int g_blocks = (N + 3) / 4;
    const int nchunksN = (N + SCAN_CHUNK - 1) / SCAN_CHUNK;
    const int nchunksJ = (2 * HL + SCAN_CHUNK - 1) / SCAN_CHUNK;

    // ---- joint bucket histograms (dst + src) and joint scan
    partAB<<<G, tb, 0, stream>>>(src, dst, histJ, E, G, NB, HL);
    scanA<<<nchunksJ, tb, 0, stream>>>(histJ, 2 * HL);
    scanB<<<1, 128, 0, stream>>>(nchunksJ);
    scanC<<<nchunksJ, tb, 0, stream>>>(histJ, histJs, 2 * HL);

    // ---- bucket-major reorder for both partitions
    partCJ<<<G, tb, 0, stream>>>(src, dst, histJs, ebufS, ebufD, ebufK, E, G, NB, HL);

    // ---- per-node degrees (coalesced, no global atomics) + rs_src
    partDcount<<<NB, tb, 0, stream>>>(ebufD, ebufK, histJs, cnt_dst, rs_src, E, G, NB, HL, N);

    // ---- offs = exclusive scan of cnt_dst
    scanA<<<nchunksN, tb, 0, stream>>>(cnt_dst, N);
    scanB<<<1, 128, 0, stream>>>(nchunksN);
    scanC<<<nchunksN, tb, 0, stream>>>(cnt_dst, offs, N);

    // ---- CSR scatter
    partD2<<<NB, tb, 0, stream>>>(ebufS, ebufD, histJs, offs, sortedSrc, E, G, NB, N);

    // ---- layer 1: h = relu((x+S)@W1_1 + (x*S)@W2_1), h lives in d_out
    gather_kernel<<<g_blocks, tb, 0, stream>>>(offs, cnt_dst, sortedSrc, rs_src, x, S, N);
    combine_kernel<<<n_blocks, tb, 0, stream>>>(x, S, W1_1, W2_1, out, N, 1);

    // ---- layer 2: out = (h+S)@W1_2 + (h*S)@W2_2
    gather_kernel<<<g_blocks, tb, 0, stream>>>(offs, cnt_dst, sortedSrc, rs_src, out, S, N);
    combine_kernel<<<n_blocks, tb, 0, stream>>>(out, S, W1_2, W2_2, out, N, 0);
}

// Round 7
// 464.185 us; speedup vs baseline: 2.8964x; 2.8964x over previous
//
#include <hip/hip_runtime.h>

#define D 64
#define SCAN_CHUNK 1024
#define MAX_CHUNKS 128
#define BSHIFT 9                 // 512 nodes per bucket
#define BNODES (1 << BSHIFT)
#define CHUNK 8192               // edges per partition block

__device__ int g_partials[MAX_CHUNKS];

// ------------------------------------------------ exclusive scan (3 kernels)
__global__ __launch_bounds__(256) void scanA(const int* __restrict__ cnt, int n) {
    __shared__ int red[256];
    int b = blockIdx.x, t = threadIdx.x;
    int base = b * SCAN_CHUNK + t * 4;
    int s = 0;
#pragma unroll
    for (int j = 0; j < 4; ++j) {
        int i = base + j;
        if (i < n) s += cnt[i];
    }
    red[t] = s;
    __syncthreads();
    for (int off = 128; off > 0; off >>= 1) {
        if (t < off) red[t] += red[t + off];
        __syncthreads();
    }
    if (t == 0) g_partials[b] = red[0];
}

__global__ __launch_bounds__(128) void scanB(int nchunks) {
    __shared__ int sh[MAX_CHUNKS];
    int t = threadIdx.x;
    int v = (t < nchunks) ? g_partials[t] : 0;
    sh[t] = v;
    __syncthreads();
    for (int off = 1; off < MAX_CHUNKS; off <<= 1) {
        int a = (t >= off) ? sh[t - off] : 0;
        __syncthreads();
        sh[t] += a;
        __syncthreads();
    }
    if (t < nchunks) g_partials[t] = sh[t] - v;  // exclusive
}

// out-of-place: offs[i] = exclusive_prefix(cnt)[i]  (cnt preserved)
__global__ __launch_bounds__(256) void scanC(const int* __restrict__ cnt,
                                             int* __restrict__ offs, int n) {
    __shared__ int sums[256];
    int b = blockIdx.x, t = threadIdx.x;
    int base = b * SCAN_CHUNK + t * 4;
    int v[4];
    int tot = 0;
#pragma unroll
    for (int j = 0; j < 4; ++j) {
        int i = base + j;
        v[j] = (i < n) ? cnt[i] : 0;
        tot += v[j];
    }
    sums[t] = tot;
    __syncthreads();
    for (int off = 1; off < 256; off <<= 1) {
        int a = (t >= off) ? sums[t - off] : 0;
        __syncthreads();
        sums[t] += a;
        __syncthreads();
    }
    int run = sums[t] - tot + g_partials[b];
#pragma unroll
    for (int j = 0; j < 4; ++j) {
        int i = base + j;
        if (i < n) offs[i] = run;
        run += v[j];
    }
}

// ------------------------------------------------ partAB: per-(chunk,bucket) counts for dst AND src
__global__ __launch_bounds__(256) void partAB(const int* __restrict__ src,
                                              const int* __restrict__ dst,
                                              int* __restrict__ histJ,
                                              int E, int G, int NB, int HL) {
    __shared__ int hD[256], hS[256];
    int g = blockIdx.x;
    hD[threadIdx.x] = 0;
    hS[threadIdx.x] = 0;
    __syncthreads();
    int base = g * CHUNK;
    int lim = min(E - base, CHUNK);
    for (int i = threadIdx.x; i < lim; i += 256) {
        atomicAdd(&hD[dst[base + i] >> BSHIFT], 1);
        atomicAdd(&hS[src[base + i] >> BSHIFT], 1);
    }
    __syncthreads();
    if (threadIdx.x < NB) {
        histJ[threadIdx.x * G + g] = hD[threadIdx.x];
        histJ[HL + threadIdx.x * G + g] = hS[threadIdx.x];
    }
}

// ------------------------------------------------ partCJ: bucket-major reorder for both partitions (SoA)
__global__ __launch_bounds__(256) void partCJ(const int* __restrict__ src,
                                              const int* __restrict__ dst,
                                              const int* __restrict__ histJs,
                                              int* __restrict__ ebufS, int* __restrict__ ebufD,
                                              int* __restrict__ ebufK,
                                              int E, int G, int NB, int HL) {
    __shared__ int curD[256], curK[256];
    int g = blockIdx.x;
    if (threadIdx.x < NB) {
        curD[threadIdx.x] = histJs[threadIdx.x * G + g];
        curK[threadIdx.x] = histJs[HL + threadIdx.x * G + g];
    }
    __syncthreads();
    int base = g * CHUNK;
    int lim = min(E - base, CHUNK);
    for (int i = threadIdx.x; i < lim; i += 256) {
        int d = dst[base + i];
        int s = src[base + i];
        int pD = atomicAdd(&curD[d >> BSHIFT], 1);
        ebufS[pD] = s;
        ebufD[pD] = d;
        int pK = atomicAdd(&curK[s >> BSHIFT], 1) - E;  // src positions offset by E in joint scan
        ebufK[pK] = s;
    }
}

// ------------------------------------------------ partDcount: per-bucket node degrees (LDS), coalesced writes
__global__ __launch_bounds__(256) void partDcount(const int* __restrict__ ebufD,
                                                  const int* __restrict__ ebufK,
                                                  const int* __restrict__ histJs,
                                                  int* __restrict__ cnt_dst, float* __restrict__ rs_src,
                                                  int E, int G, int NB, int HL, int N) {
    __shared__ int cntD[BNODES], cntS[BNODES];
    int b = blockIdx.x;
    int nbase = b << BSHIFT;
    for (int i = threadIdx.x; i < BNODES; i += 256) { cntD[i] = 0; cntS[i] = 0; }
    __syncthreads();
    int dS = histJs[b * G];
    int dE = (b + 1 < NB) ? histJs[(b + 1) * G] : E;
    for (int p = dS + threadIdx.x; p < dE; p += 256)
        atomicAdd(&cntD[ebufD[p] - nbase], 1);
    int kS = histJs[HL + b * G] - E;
    int kE = (b + 1 < NB) ? histJs[HL + (b + 1) * G] - E : E;
    for (int p = kS + threadIdx.x; p < kE; p += 256)
        atomicAdd(&cntS[ebufK[p] - nbase], 1);
    __syncthreads();
    for (int i = threadIdx.x; i < BNODES; i += 256) {
        int node = nbase + i;
        if (node < N) {
            cnt_dst[node] = cntD[i];
            rs_src[node] = rsqrtf((float)max(cntS[i], 1));
        }
    }
}

// ------------------------------------------------ partD2: per-bucket local scatter (LDS cursors)
__global__ __launch_bounds__(256) void partD2(const int* __restrict__ ebufS,
                                              const int* __restrict__ ebufD,
                                              const int* __restrict__ histJs,
                                              const int* __restrict__ offs,
                                              int* __restrict__ sortedSrc,
                                              int E, int G, int NB, int N) {
    __shared__ int cur[BNODES];
    int b = blockIdx.x;
    int nbase = b << BSHIFT;
    for (int i = threadIdx.x; i < BNODES; i += 256) {
        int node = nbase + i;
        cur[i] = (node < N) ? offs[node] : 0;
    }
    __syncthreads();
    int dS = histJs[b * G];
    int dE = (b + 1 < NB) ? histJs[(b + 1) * G] : E;
    for (int p = dS + threadIdx.x; p < dE; p += 256) {
        int d = ebufD[p];
        int s = ebufS[p];
        int pos = atomicAdd(&cur[d - nbase], 1);
        sortedSrc[pos] = s;
    }
}

// ------------------------------------------------ gather: S[i] = rs_dst[i] * sum rs_src[sj] * X[sj]
__global__ __launch_bounds__(256) void gather_kernel(
    const int* __restrict__ offs, const int* __restrict__ cnt_dst,
    const int* __restrict__ sortedSrc, const float* __restrict__ rs_src,
    const float* __restrict__ X, float* __restrict__ S, int n) {
    int lane = threadIdx.x & 63;
    int node = blockIdx.x * 4 + (threadIdx.x >> 6);
    if (node >= n) return;
    int start = offs[node];
    int cnt = cnt_dst[node];
    int end = start + cnt;
    float acc = 0.0f;
    int p = start;
    for (; p + 8 <= end; p += 8) {
        int idx[8];
        float w[8];
        float r[8];
#pragma unroll
        for (int j = 0; j < 8; ++j) idx[j] = sortedSrc[p + j];
#pragma unroll
        for (int j = 0; j < 8; ++j) w[j] = rs_src[idx[j]];
#pragma unroll
        for (int j = 0; j < 8; ++j) r[j] = X[(size_t)idx[j] * D + lane];
#pragma unroll
        for (int j = 0; j < 8; ++j) acc = fmaf(w[j], r[j], acc);
    }
    if (p < end) {  // clamped predicated tail: loads stay independent
        int idx[8];
        float w[8];
        float r[8];
#pragma unroll
        for (int j = 0; j < 8; ++j) {
            int q = p + j;
            int qc = (q < end) ? q : (end - 1);
            idx[j] = sortedSrc[qc];
        }
#pragma unroll
        for (int j = 0; j < 8; ++j) w[j] = (p + j < end) ? rs_src[idx[j]] : 0.0f;
#pragma unroll
        for (int j = 0; j < 8; ++j) r[j] = X[(size_t)idx[j] * D + lane];
#pragma unroll
        for (int j = 0; j < 8; ++j) acc = fmaf(w[j], r[j], acc);
    }
    float rd = rsqrtf((float)max(cnt, 1));
    S[(size_t)node * D + lane] = acc * rd;
}

// ------------------------------------------------ combine: Out = (X+S)@W1 + (X*S)@W2
// R4 structure (runtime kk-loop, unrolled c-loop -> static acc indices, streamed
// float4 x/S) + __launch_bounds__(256,2): 256-VGPR budget so the allocator does
// NOT spill-for-occupancy (R4: VGPR=52 -> ~60MB scratch; R5 mega-unroll: ~1GB).
// Layer-2 X==Out alias safe: each thread reads only its own row, all reads
// precede its stores.
__global__ __launch_bounds__(256, 2) void combine_kernel(
    const float* X, const float* S,
    const float* __restrict__ W1, const float* __restrict__ W2,
    float* Out, int n, int relu_flag) {
    int row = blockIdx.x * blockDim.x + threadIdx.x;
    if (row >= n) return;
    const float4* x4 = (const float4*)(X + (size_t)row * D);
    const float4* s4 = (const float4*)(S + (size_t)row * D);
    float acc[D];
#pragma unroll
    for (int c = 0; c < D; ++c) acc[c] = 0.0f;

    float4 xc = x4[0], sc = s4[0];
    for (int kk = 0; kk < 16; ++kk) {
        float4 xn, sn;
        if (kk < 15) { xn = x4[kk + 1]; sn = s4[kk + 1]; }
#pragma unroll
        for (int j = 0; j < 4; ++j) {
            int k = (kk << 2) + j;
            float xk = ((const float*)&xc)[j];
            float sk = ((const float*)&sc)[j];
            float u = xk + sk;
            float v = xk * sk;
#pragma unroll
            for (int c = 0; c < D; ++c) {
                acc[c] = fmaf(u, W1[k * D + c], acc[c]);   // wave-uniform -> s_load
                acc[c] = fmaf(v, W2[k * D + c], acc[c]);
            }
        }
        xc = xn; sc = sn;
    }
    float4* o4 = (float4*)(Out + (size_t)row * D);
#pragma unroll
    for (int cc = 0; cc < 16; ++cc) {
        float4 o;
        o.x = acc[cc * 4 + 0];
        o.y = acc[cc * 4 + 1];
        o.z = acc[cc * 4 + 2];
        o.w = acc[cc * 4 + 3];
        if (relu_flag) {
            o.x = fmaxf(o.x, 0.0f); o.y = fmaxf(o.y, 0.0f);
            o.z = fmaxf(o.z, 0.0f); o.w = fmaxf(o.w, 0.0f);
        }
        o4[cc] = o;
    }
}

extern "C" void kernel_launch(void* const* d_in, const int* in_sizes, int n_in,
                              void* d_out, int out_size, void* d_ws, size_t ws_size,
                              hipStream_t stream) {
    const float* x    = (const float*)d_in[0];
    const int*   src  = (const int*)d_in[1];
    const int*   dst  = (const int*)d_in[2];
    const float* W1_1 = (const float*)d_in[3];
    const float* W2_1 = (const float*)d_in[4];
    const float* W1_2 = (const float*)d_in[5];
    const float* W2_2 = (const float*)d_in[6];
    float* out = (float*)d_out;

    const int N = in_sizes[0] / D;
    const int E = in_sizes[1];

    const int NB = (N + BNODES - 1) >> BSHIFT;     // node buckets (196 for N=100000)
    const int G  = (E + CHUNK - 1) / CHUNK;        // partition chunks (196)
    const int HL = NB * G;

    // ws layout (4B units):
    // cnt_dst[N] | offs[N] | rs_src[N] | sortedSrc[E] | histJ[2HL] | histJs[2HL] | S[N*D]
    // ebufS/ebufD/ebufK alias S (19.2MB < 25.6MB; all dead before gather writes S).
    int*   cnt_dst   = (int*)d_ws;
    int*   offs      = cnt_dst + N;
    float* rs_src    = (float*)(cnt_dst + 2 * (size_t)N);
    int*   sortedSrc = cnt_dst + 3 * (size_t)N;
    int*   histJ     = sortedSrc + E;
    int*   histJs    = histJ + 2 * (size_t)HL;
    float* S         = (float*)(histJs + 2 * (size_t)HL);
    int*   ebufS     = (int*)S;
    int*   ebufD     = ebufS + E;
    int*   ebufK     = ebufD + E;

    const int tb = 256;
    const int n_blocks = (N + tb - 1) / tb;
    const int g_blocks = (N + 3) / 4;
    const int nchunksN = (N + SCAN_CHUNK - 1) / SCAN_CHUNK;
    const int nchunksJ = (2 * HL + SCAN_CHUNK - 1) / SCAN_CHUNK;

    // ---- joint bucket histograms (dst + src) and joint scan
    partAB<<<G, tb, 0, stream>>>(src, dst, histJ, E, G, NB, HL);
    scanA<<<nchunksJ, tb, 0, stream>>>(histJ, 2 * HL);
    scanB<<<1, 128, 0, stream>>>(nchunksJ);
    scanC<<<nchunksJ, tb, 0, stream>>>(histJ, histJs, 2 * HL);

    // ---- bucket-major reorder for both partitions
    partCJ<<<G, tb, 0, stream>>>(src, dst, histJs, ebufS, ebufD, ebufK, E, G, NB, HL);

    // ---- per-node degrees (coalesced, no global atomics) + rs_src
    partDcount<<<NB, tb, 0, stream>>>(ebufD, ebufK, histJs, cnt_dst, rs_src, E, G, NB, HL, N);

    // ---- offs = exclusive scan of cnt_dst
    scanA<<<nchunksN, tb, 0, stream>>>(cnt_dst, N);
    scanB<<<1, 128, 0, stream>>>(nchunksN);
    scanC<<<nchunksN, tb, 0, stream>>>(cnt_dst, offs, N);

    // ---- CSR scatter
    partD2<<<NB, tb, 0, stream>>>(ebufS, ebufD, histJs, offs, sortedSrc, E, G, NB, N);

    // ---- layer 1: h = relu((x+S)@W1_1 + (x*S)@W2_1), h lives in d_out
    gather_kernel<<<g_blocks, tb, 0, stream>>>(offs, cnt_dst, sortedSrc, rs_src, x, S, N);
    combine_kernel<<<n_blocks, tb, 0, stream>>>(x, S, W1_1, W2_1, out, N, 1);

    // ---- layer 2: out = (h+S)@W1_2 + (h*S)@W2_2
    gather_kernel<<<g_blocks, tb, 0, stream>>>(offs, cnt_dst, sortedSrc, rs_src, out, S, N);
    combine_kernel<<<n_blocks, tb, 0, stream>>>(out, S, W1_2, W2_2, out, N, 0);
}

// Round 8
// 421.270 us; speedup vs baseline: 3.1915x; 1.1019x over previous
//
#include <hip/hip_runtime.h>

#define D 64
#define SCAN_CHUNK 1024
#define MAX_CHUNKS 128
#define BSHIFT 9                 // 512 nodes per bucket
#define BNODES (1 << BSHIFT)
#define CHUNK 8192               // edges per partition block

__device__ int g_partials[MAX_CHUNKS];

// ------------------------------------------------ exclusive scan (3 kernels)
__global__ __launch_bounds__(256) void scanA(const int* __restrict__ cnt, int n) {
    __shared__ int red[256];
    int b = blockIdx.x, t = threadIdx.x;
    int base = b * SCAN_CHUNK + t * 4;
    int s = 0;
#pragma unroll
    for (int j = 0; j < 4; ++j) {
        int i = base + j;
        if (i < n) s += cnt[i];
    }
    red[t] = s;
    __syncthreads();
    for (int off = 128; off > 0; off >>= 1) {
        if (t < off) red[t] += red[t + off];
        __syncthreads();
    }
    if (t == 0) g_partials[b] = red[0];
}

__global__ __launch_bounds__(128) void scanB(int nchunks) {
    __shared__ int sh[MAX_CHUNKS];
    int t = threadIdx.x;
    int v = (t < nchunks) ? g_partials[t] : 0;
    sh[t] = v;
    __syncthreads();
    for (int off = 1; off < MAX_CHUNKS; off <<= 1) {
        int a = (t >= off) ? sh[t - off] : 0;
        __syncthreads();
        sh[t] += a;
        __syncthreads();
    }
    if (t < nchunks) g_partials[t] = sh[t] - v;  // exclusive
}

// out-of-place: offs[i] = exclusive_prefix(cnt)[i]  (cnt preserved)
__global__ __launch_bounds__(256) void scanC(const int* __restrict__ cnt,
                                             int* __restrict__ offs, int n) {
    __shared__ int sums[256];
    int b = blockIdx.x, t = threadIdx.x;
    int base = b * SCAN_CHUNK + t * 4;
    int v[4];
    int tot = 0;
#pragma unroll
    for (int j = 0; j < 4; ++j) {
        int i = base + j;
        v[j] = (i < n) ? cnt[i] : 0;
        tot += v[j];
    }
    sums[t] = tot;
    __syncthreads();
    for (int off = 1; off < 256; off <<= 1) {
        int a = (t >= off) ? sums[t - off] : 0;
        __syncthreads();
        sums[t] += a;
        __syncthreads();
    }
    int run = sums[t] - tot + g_partials[b];
#pragma unroll
    for (int j = 0; j < 4; ++j) {
        int i = base + j;
        if (i < n) offs[i] = run;
        run += v[j];
    }
}

// ------------------------------------------------ partAB: per-(chunk,bucket) counts for dst AND src
__global__ __launch_bounds__(256) void partAB(const int* __restrict__ src,
                                              const int* __restrict__ dst,
                                              int* __restrict__ histJ,
                                              int E, int G, int NB, int HL) {
    __shared__ int hD[256], hS[256];
    int g = blockIdx.x;
    hD[threadIdx.x] = 0;
    hS[threadIdx.x] = 0;
    __syncthreads();
    int base = g * CHUNK;
    int lim = min(E - base, CHUNK);
    for (int i = threadIdx.x; i < lim; i += 256) {
        atomicAdd(&hD[dst[base + i] >> BSHIFT], 1);
        atomicAdd(&hS[src[base + i] >> BSHIFT], 1);
    }
    __syncthreads();
    if (threadIdx.x < NB) {
        histJ[threadIdx.x * G + g] = hD[threadIdx.x];
        histJ[HL + threadIdx.x * G + g] = hS[threadIdx.x];
    }
}

// ------------------------------------------------ partCJ: bucket-major reorder for both partitions (SoA)
__global__ __launch_bounds__(256) void partCJ(const int* __restrict__ src,
                                              const int* __restrict__ dst,
                                              const int* __restrict__ histJs,
                                              int* __restrict__ ebufS, int* __restrict__ ebufD,
                                              int* __restrict__ ebufK,
                                              int E, int G, int NB, int HL) {
    __shared__ int curD[256], curK[256];
    int g = blockIdx.x;
    if (threadIdx.x < NB) {
        curD[threadIdx.x] = histJs[threadIdx.x * G + g];
        curK[threadIdx.x] = histJs[HL + threadIdx.x * G + g];
    }
    __syncthreads();
    int base = g * CHUNK;
    int lim = min(E - base, CHUNK);
    for (int i = threadIdx.x; i < lim; i += 256) {
        int d = dst[base + i];
        int s = src[base + i];
        int pD = atomicAdd(&curD[d >> BSHIFT], 1);
        ebufS[pD] = s;
        ebufD[pD] = d;
        int pK = atomicAdd(&curK[s >> BSHIFT], 1) - E;  // src positions offset by E in joint scan
        ebufK[pK] = s;
    }
}

// ------------------------------------------------ partDcount: per-bucket node degrees (LDS), coalesced writes
__global__ __launch_bounds__(256) void partDcount(const int* __restrict__ ebufD,
                                                  const int* __restrict__ ebufK,
                                                  const int* __restrict__ histJs,
                                                  int* __restrict__ cnt_dst, float* __restrict__ rs_src,
                                                  int E, int G, int NB, int HL, int N) {
    __shared__ int cntD[BNODES], cntS[BNODES];
    int b = blockIdx.x;
    int nbase = b << BSHIFT;
    for (int i = threadIdx.x; i < BNODES; i += 256) { cntD[i] = 0; cntS[i] = 0; }
    __syncthreads();
    int dS = histJs[b * G];
    int dE = (b + 1 < NB) ? histJs[(b + 1) * G] : E;
    for (int p = dS + threadIdx.x; p < dE; p += 256)
        atomicAdd(&cntD[ebufD[p] - nbase], 1);
    int kS = histJs[HL + b * G] - E;
    int kE = (b + 1 < NB) ? histJs[HL + (b + 1) * G] - E : E;
    for (int p = kS + threadIdx.x; p < kE; p += 256)
        atomicAdd(&cntS[ebufK[p] - nbase], 1);
    __syncthreads();
    for (int i = threadIdx.x; i < BNODES; i += 256) {
        int node = nbase + i;
        if (node < N) {
            cnt_dst[node] = cntD[i];
            rs_src[node] = rsqrtf((float)max(cntS[i], 1));
        }
    }
}

// ------------------------------------------------ partD2: per-bucket local scatter (LDS cursors)
__global__ __launch_bounds__(256) void partD2(const int* __restrict__ ebufS,
                                              const int* __restrict__ ebufD,
                                              const int* __restrict__ histJs,
                                              const int* __restrict__ offs,
                                              int* __restrict__ sortedSrc,
                                              int E, int G, int NB, int N) {
    __shared__ int cur[BNODES];
    int b = blockIdx.x;
    int nbase = b << BSHIFT;
    for (int i = threadIdx.x; i < BNODES; i += 256) {
        int node = nbase + i;
        cur[i] = (node < N) ? offs[node] : 0;
    }
    __syncthreads();
    int dS = histJs[b * G];
    int dE = (b + 1 < NB) ? histJs[(b + 1) * G] : E;
    for (int p = dS + threadIdx.x; p < dE; p += 256) {
        int d = ebufD[p];
        int s = ebufS[p];
        int pos = atomicAdd(&cur[d - nbase], 1);
        sortedSrc[pos] = s;
    }
}

// ------------------------------------------------ gather: S[i] = rs_dst[i] * sum rs_src[sj] * X[sj]
__global__ __launch_bounds__(256) void gather_kernel(
    const int* __restrict__ offs, const int* __restrict__ cnt_dst,
    const int* __restrict__ sortedSrc, const float* __restrict__ rs_src,
    const float* __restrict__ X, float* __restrict__ S, int n) {
    int lane = threadIdx.x & 63;
    int node = blockIdx.x * 4 + (threadIdx.x >> 6);
    if (node >= n) return;
    int start = offs[node];
    int cnt = cnt_dst[node];
    int end = start + cnt;
    float acc = 0.0f;
    int p = start;
    for (; p + 8 <= end; p += 8) {
        int idx[8];
        float w[8];
        float r[8];
#pragma unroll
        for (int j = 0; j < 8; ++j) idx[j] = sortedSrc[p + j];
#pragma unroll
        for (int j = 0; j < 8; ++j) w[j] = rs_src[idx[j]];
#pragma unroll
        for (int j = 0; j < 8; ++j) r[j] = X[(size_t)idx[j] * D + lane];
#pragma unroll
        for (int j = 0; j < 8; ++j) acc = fmaf(w[j], r[j], acc);
    }
    if (p < end) {  // clamped predicated tail: loads stay independent
        int idx[8];
        float w[8];
        float r[8];
#pragma unroll
        for (int j = 0; j < 8; ++j) {
            int q = p + j;
            int qc = (q < end) ? q : (end - 1);
            idx[j] = sortedSrc[qc];
        }
#pragma unroll
        for (int j = 0; j < 8; ++j) w[j] = (p + j < end) ? rs_src[idx[j]] : 0.0f;
#pragma unroll
        for (int j = 0; j < 8; ++j) r[j] = X[(size_t)idx[j] * D + lane];
#pragma unroll
        for (int j = 0; j < 8; ++j) acc = fmaf(w[j], r[j], acc);
    }
    float rd = rsqrtf((float)max(cnt, 1));
    S[(size_t)node * D + lane] = acc * rd;
}

// ------------------------------------------------ combine: Out = (X+S)@W1 + (X*S)@W2
// NO ARRAYS: 16 named float4 accumulators (every index compile-time constant —
// rule #20: runtime-indexed arrays go to scratch; R4/R6 VGPR=52 + 58MB scratch
// traffic proved acc[64] was in local memory). Runtime kk-loop (#pragma unroll 1,
// R5 showed mega-unroll catastrophic). W loads: uniform base + imm offsets in
// UNIFORM control flow (row clamped, store guarded) -> s_load_dwordx4.
// Layer-2 X==Out alias safe: thread reads only its own row before storing it;
// clamped threads never store.
#define CK_COLS(Ai, i, u, v, wrow1, wrow2)                                \
    {                                                                     \
        float4 w1v = *(const float4*)((wrow1) + (i) * 4);                 \
        float4 w2v = *(const float4*)((wrow2) + (i) * 4);                 \
        Ai.x = fmaf(u, w1v.x, fmaf(v, w2v.x, Ai.x));                      \
        Ai.y = fmaf(u, w1v.y, fmaf(v, w2v.y, Ai.y));                      \
        Ai.z = fmaf(u, w1v.z, fmaf(v, w2v.z, Ai.z));                      \
        Ai.w = fmaf(u, w1v.w, fmaf(v, w2v.w, Ai.w));                      \
    }
#define CK_ALL16(u, v, wrow1, wrow2)                                      \
    CK_COLS(A0, 0, u, v, wrow1, wrow2)                                    \
    CK_COLS(A1, 1, u, v, wrow1, wrow2)                                    \
    CK_COLS(A2, 2, u, v, wrow1, wrow2)                                    \
    CK_COLS(A3, 3, u, v, wrow1, wrow2)                                    \
    CK_COLS(A4, 4, u, v, wrow1, wrow2)                                    \
    CK_COLS(A5, 5, u, v, wrow1, wrow2)                                    \
    CK_COLS(A6, 6, u, v, wrow1, wrow2)                                    \
    CK_COLS(A7, 7, u, v, wrow1, wrow2)                                    \
    CK_COLS(A8, 8, u, v, wrow1, wrow2)                                    \
    CK_COLS(A9, 9, u, v, wrow1, wrow2)                                    \
    CK_COLS(A10, 10, u, v, wrow1, wrow2)                                  \
    CK_COLS(A11, 11, u, v, wrow1, wrow2)                                  \
    CK_COLS(A12, 12, u, v, wrow1, wrow2)                                  \
    CK_COLS(A13, 13, u, v, wrow1, wrow2)                                  \
    CK_COLS(A14, 14, u, v, wrow1, wrow2)                                  \
    CK_COLS(A15, 15, u, v, wrow1, wrow2)
#define CK_RELU(Ai)                                                       \
    {                                                                     \
        Ai.x = fmaxf(Ai.x, 0.0f); Ai.y = fmaxf(Ai.y, 0.0f);               \
        Ai.z = fmaxf(Ai.z, 0.0f); Ai.w = fmaxf(Ai.w, 0.0f);               \
    }

__global__ __launch_bounds__(256, 2) void combine_kernel(
    const float* X, const float* S,
    const float* __restrict__ W1, const float* __restrict__ W2,
    float* Out, int n, int relu_flag) {
    int row0 = blockIdx.x * blockDim.x + threadIdx.x;
    int row = min(row0, n - 1);           // uniform CF: no early return
    const float4* x4 = (const float4*)(X + (size_t)row * D);
    const float4* s4 = (const float4*)(S + (size_t)row * D);

    float4 A0 = make_float4(0.f, 0.f, 0.f, 0.f);
    float4 A1 = A0, A2 = A0, A3 = A0, A4 = A0, A5 = A0, A6 = A0, A7 = A0;
    float4 A8 = A0, A9 = A0, A10 = A0, A11 = A0, A12 = A0, A13 = A0, A14 = A0, A15 = A0;

    float4 xc = x4[0], sc = s4[0];
#pragma unroll 1
    for (int kk = 0; kk < 16; ++kk) {
        float4 xn, sn;
        if (kk < 15) { xn = x4[kk + 1]; sn = s4[kk + 1]; }
        const float* w1k = W1 + kk * 4 * D;   // uniform -> scalar base
        const float* w2k = W2 + kk * 4 * D;
        {
            float u = xc.x + sc.x, v = xc.x * sc.x;
            CK_ALL16(u, v, w1k + 0 * D, w2k + 0 * D)
        }
        {
            float u = xc.y + sc.y, v = xc.y * sc.y;
            CK_ALL16(u, v, w1k + 1 * D, w2k + 1 * D)
        }
        {
            float u = xc.z + sc.z, v = xc.z * sc.z;
            CK_ALL16(u, v, w1k + 2 * D, w2k + 2 * D)
        }
        {
            float u = xc.w + sc.w, v = xc.w * sc.w;
            CK_ALL16(u, v, w1k + 3 * D, w2k + 3 * D)
        }
        xc = xn; sc = sn;
    }

    if (row0 < n) {
        if (relu_flag) {
            CK_RELU(A0)  CK_RELU(A1)  CK_RELU(A2)  CK_RELU(A3)
            CK_RELU(A4)  CK_RELU(A5)  CK_RELU(A6)  CK_RELU(A7)
            CK_RELU(A8)  CK_RELU(A9)  CK_RELU(A10) CK_RELU(A11)
            CK_RELU(A12) CK_RELU(A13) CK_RELU(A14) CK_RELU(A15)
        }
        float4* o4 = (float4*)(Out + (size_t)row * D);
        o4[0] = A0;   o4[1] = A1;   o4[2] = A2;   o4[3] = A3;
        o4[4] = A4;   o4[5] = A5;   o4[6] = A6;   o4[7] = A7;
        o4[8] = A8;   o4[9] = A9;   o4[10] = A10; o4[11] = A11;
        o4[12] = A12; o4[13] = A13; o4[14] = A14; o4[15] = A15;
    }
}

extern "C" void kernel_launch(void* const* d_in, const int* in_sizes, int n_in,
                              void* d_out, int out_size, void* d_ws, size_t ws_size,
                              hipStream_t stream) {
    const float* x    = (const float*)d_in[0];
    const int*   src  = (const int*)d_in[1];
    const int*   dst  = (const int*)d_in[2];
    const float* W1_1 = (const float*)d_in[3];
    const float* W2_1 = (const float*)d_in[4];
    const float* W1_2 = (const float*)d_in[5];
    const float* W2_2 = (const float*)d_in[6];
    float* out = (float*)d_out;

    const int N = in_sizes[0] / D;
    const int E = in_sizes[1];

    const int NB = (N + BNODES - 1) >> BSHIFT;     // node buckets (196 for N=100000)
    const int G  = (E + CHUNK - 1) / CHUNK;        // partition chunks (196)
    const int HL = NB * G;

    // ws layout (4B units):
    // cnt_dst[N] | offs[N] | rs_src[N] | sortedSrc[E] | histJ[2HL] | histJs[2HL] | S[N*D]
    // ebufS/ebufD/ebufK alias S (19.2MB < 25.6MB; all dead before gather writes S).
    int*   cnt_dst   = (int*)d_ws;
    int*   offs      = cnt_dst + N;
    float* rs_src    = (float*)(cnt_dst + 2 * (size_t)N);
    int*   sortedSrc = cnt_dst + 3 * (size_t)N;
    int*   histJ     = sortedSrc + E;
    int*   histJs    = histJ + 2 * (size_t)HL;
    float* S         = (float*)(histJs + 2 * (size_t)HL);
    int*   ebufS     = (int*)S;
    int*   ebufD     = ebufS + E;
    int*   ebufK     = ebufD + E;

    const int tb = 256;
    const int n_blocks = (N + tb - 1) / tb;
    const int g_blocks = (N + 3) / 4;
    const int nchunksN = (N + SCAN_CHUNK - 1) / SCAN_CHUNK;
    const int nchunksJ = (2 * HL + SCAN_CHUNK - 1) / SCAN_CHUNK;

    // ---- joint bucket histograms (dst + src) and joint scan
    partAB<<<G, tb, 0, stream>>>(src, dst, histJ, E, G, NB, HL);
    scanA<<<nchunksJ, tb, 0, stream>>>(histJ, 2 * HL);
    scanB<<<1, 128, 0, stream>>>(nchunksJ);
    scanC<<<nchunksJ, tb, 0, stream>>>(histJ, histJs, 2 * HL);

    // ---- bucket-major reorder for both partitions
    partCJ<<<G, tb, 0, stream>>>(src, dst, histJs, ebufS, ebufD, ebufK, E, G, NB, HL);

    // ---- per-node degrees (coalesced, no global atomics) + rs_src
    partDcount<<<NB, tb, 0, stream>>>(ebufD, ebufK, histJs, cnt_dst, rs_src, E, G, NB, HL, N);

    // ---- offs = exclusive scan of cnt_dst
    scanA<<<nchunksN, tb, 0, stream>>>(cnt_dst, N);
    scanB<<<1, 128, 0, stream>>>(nchunksN);
    scanC<<<nchunksN, tb, 0, stream>>>(cnt_dst, offs, N);

    // ---- CSR scatter
    partD2<<<NB, tb, 0, stream>>>(ebufS, ebufD, histJs, offs, sortedSrc, E, G, NB, N);

    // ---- layer 1: h = relu((x+S)@W1_1 + (x*S)@W2_1), h lives in d_out
    gather_kernel<<<g_blocks, tb, 0, stream>>>(offs, cnt_dst, sortedSrc, rs_src, x, S, N);
    combine_kernel<<<n_blocks, tb, 0, stream>>>(x, S, W1_1, W2_1, out, N, 1);

    // ---- layer 2: out = (h+S)@W1_2 + (h*S)@W2_2
    gather_kernel<<<g_blocks, tb, 0, stream>>>(offs, cnt_dst, sortedSrc, rs_src, out, S, N);
    combine_kernel<<<n_blocks, tb, 0, stream>>>(out, S, W1_2, W2_2, out, N, 0);
}